// Round 11
// baseline (357.472 us; speedup 1.0000x reference)
//
#include <hip/hip_runtime.h>

#define LOG2E 1.44269504088896340736f

__device__ __forceinline__ float vexp2(float x){ float r; asm("v_exp_f32 %0, %1" : "=v"(r) : "v"(x)); return r; }
__device__ __forceinline__ float vrcp (float x){ float r; asm("v_rcp_f32 %0, %1" : "=v"(r) : "v"(x)); return r; }
template<int OFF> __device__ __forceinline__ float dsw(float v){
  return __int_as_float(__builtin_amdgcn_ds_swizzle(__float_as_int(v), OFF));
}
// xor-exchange within 32-group (and=0x1F)
#define SWX(m)  dsw<((m)<<10)|0x1F>
// broadcast slot k of own 16-half within the 32-group: src = (lane&16)|k
#define BC16(k) dsw<((k)<<5)|0x10>
__device__ __forceinline__ float sigm(float x){ return vrcp(1.0f + vexp2(x * (-LOG2E))); }
__device__ __forceinline__ float tanh_f(float x){
  float s = vrcp(1.0f + vexp2(x * (-2.0f*LOG2E)));
  return s + s - 1.0f;
}

// Layer-skewed software pipeline: iteration i computes {e1(i), e2(i-1), e3(i-2)}
// (decoder: {d1(i), d2(i-1), d3(i-2), lin(i-3)}). Stages depend only on
// previous-iteration state, so their latency chains interleave.
// NOTE: this kernel sits exactly on the 128-VGPR occupancy cliff (VGPR>128
// with 256-thread blocks -> 1 block/CU, measured R7/R10). launch_bounds(256,4)
// pins the allocator at 128.
__global__ void __launch_bounds__(256, 4)
lstm_ae_fused(const float* __restrict__ x,
              const float* __restrict__ e1Wi, const float* __restrict__ e1Wh, const float* __restrict__ e1bi, const float* __restrict__ e1bh,
              const float* __restrict__ e2Wi, const float* __restrict__ e2Wh, const float* __restrict__ e2bi, const float* __restrict__ e2bh,
              const float* __restrict__ e3Wi, const float* __restrict__ e3Wh, const float* __restrict__ e3bi, const float* __restrict__ e3bh,
              const float* __restrict__ d1Wi, const float* __restrict__ d1Wh, const float* __restrict__ d1bi, const float* __restrict__ d1bh,
              const float* __restrict__ d2Wi, const float* __restrict__ d2Wh, const float* __restrict__ d2bi, const float* __restrict__ d2bh,
              const float* __restrict__ d3Wi, const float* __restrict__ d3Wh, const float* __restrict__ d3bi, const float* __restrict__ d3bh,
              const float* __restrict__ Wout, const float* __restrict__ bout,
              float* __restrict__ out)
{
  const int tid  = threadIdx.x;
  const int lane = tid & 63;
  const int wv   = tid >> 6;                 // wave 0..3
  const int gw   = blockIdx.x*4 + wv;        // global wave
  const int bA   = gw*2, bB = gw*2 + 1;
  const float* __restrict__ xbA = x + (size_t)bA * 4096;
  const float* __restrict__ xbB = x + (size_t)bB * 4096;
  float* __restrict__ obA = out + (size_t)bA * 4096;
  float* __restrict__ obB = out + (size_t)bB * 4096;

  // ---------------- LDS (39936 B -> 2 blocks/CU) ----------------
  __shared__ float s_e1[13*64*4];   // per-lane quads: 0-7 w1i, 8-11 w1h, 12.x eb1
  __shared__ float s_e2[16*20];
  __shared__ float s_eb2[16];
  __shared__ float s_e3[4*8];
  __shared__ float s_d1[16*8];
  __shared__ float s_d2[32*20];
  __shared__ float s_d3[7*64*4];    // 0-1 wd3i, 2-5 wd3h, 6.x bd3
  __shared__ float s_wo[32*20];
  __shared__ float s_x [4][512];    // per wave: [0..255] A 8-step chunk, [256..511] B
  __shared__ float s_h1[4][64];     // e1 h state: A 0-15, B 16-31
  __shared__ float s_g1[4][64];     // decoder hd1
  __shared__ float s_g2[4][64];     // decoder hd2
  __shared__ float s_g3[4][64];     // decoder hd3

  // ---------------- one-time weight staging (g-gate rows pre-scaled x2) ----------------
  if (tid < 64){
    const int l = tid;
    const float A1l = (l>=32 && l<48) ? 2.f : 1.f;
    for (int k=0;k<32;++k) s_e1[((k>>2)*64+l)*4+(k&3)]      = e1Wi[l*32+k]*A1l;
    for (int k=0;k<16;++k) s_e1[(((k>>2)+8)*64+l)*4+(k&3)]  = e1Wh[l*16+k]*A1l;
    s_e1[(12*64+l)*4] = (e1bi[l]+e1bh[l])*A1l;
    for (int k=0;k<8;++k)  s_d3[((k>>2)*64+l)*4+(k&3)]      = d3Wi[l*8+k]*A1l;
    for (int k=0;k<16;++k) s_d3[(((k>>2)+2)*64+l)*4+(k&3)]  = d3Wh[l*16+k]*A1l;
    s_d3[(6*64+l)*4] = (d3bi[l]+d3bh[l])*A1l;
    if (l < 16){
      const float A2l = (l>=8 && l<12) ? 2.f : 1.f;
      for (int k=0;k<16;++k) s_e2[l*20+k]    = e2Wi[l*16+k]*A2l;
      for (int k=0;k<4;++k)  s_e2[l*20+16+k] = e2Wh[l*4+k]*A2l;
      s_eb2[l] = (e2bi[l]+e2bh[l])*A2l;
      for (int k=0;k<4;++k)  s_d1[l*8+k] = d1Wh[l*4+k]*A2l;
      s_d1[l*8+4] = d1Wi[l]*A2l;
      s_d1[l*8+5] = (d1bi[l]+d1bh[l])*A2l;
    }
    if (l < 4){
      const float A3l = (l==2) ? 2.f : 1.f;
      for (int k=0;k<4;++k) s_e3[l*8+k] = e3Wi[l*4+k]*A3l;
      s_e3[l*8+4] = e3Wh[l]*A3l;
      s_e3[l*8+5] = (e3bi[l]+e3bh[l])*A3l;
    }
    if (l < 32){
      const float AD2l = (l>=16 && l<24) ? 2.f : 1.f;
      for (int k=0;k<4;++k) s_d2[l*20+k]   = d2Wi[l*4+k]*AD2l;
      for (int k=0;k<8;++k) s_d2[l*20+4+k] = d2Wh[l*8+k]*AD2l;
      s_d2[l*20+12] = (d2bi[l]+d2bh[l])*AD2l;
      for (int k=0;k<16;++k) s_wo[l*20+k] = Wout[l*16+k];
      s_wo[l*20+16] = bout[l];
    }
  }
  __syncthreads();

  const bool isg1 = (lane >= 32) && (lane < 48);
  const bool isg2 = ((lane & 15) >= 8) && ((lane & 15) < 12);
  const bool isg3 = ((lane & 3) == 2);
  const bool isgD2= ((lane & 31) >= 16) && ((lane & 31) < 24);
  const float A1 = isg1 ? 2.f : 1.f,  B1 = isg1 ? -1.f : 0.f;
  const float A2 = isg2 ? 2.f : 1.f,  B2 = isg2 ? -1.f : 0.f;
  const float A3 = isg3 ? 2.f : 1.f,  B3 = isg3 ? -1.f : 0.f;
  const float AD2= isgD2? 2.f : 1.f,  BD2= isgD2? -1.f : 0.f;
  const bool selA = ((lane & 16) == 0);
  const int  h16  = lane & 16;
  const int  h32  = lane & 32;
  const int  h32s = (lane & 32) >> 1;

  const float4* e1v = (const float4*)s_e1;
  const float4* d3v = (const float4*)s_d3;
  const float* r2  = &s_e2[(lane&15)*20];
  const float* r3  = &s_e3[(lane&3)*8];
  const float* rd1 = &s_d1[(lane&15)*8];
  const float* rd2 = &s_d2[(lane&31)*20];
  const float* rw  = &s_wo[(lane&31)*20];

  float h3b = 0.f;   // survives into decoder (enc)

  // ======================= ENCODER =======================
  {
    float4 w1q[8], wh1q[4];
    #pragma unroll
    for (int g=0; g<8; ++g) w1q[g] = e1v[g*64+lane];
    #pragma unroll
    for (int g=0; g<4; ++g) wh1q[g] = e1v[(8+g)*64+lane];
    const float eb1 = s_e1[(12*64+lane)*4];
    float4 w2q0 = *(const float4*)(r2);
    float4 w2q1 = *(const float4*)(r2+4);
    float4 w2q2 = *(const float4*)(r2+8);
    float4 w2q3 = *(const float4*)(r2+12);
    float4 w2q4 = *(const float4*)(r2+16);
    const float eb2 = s_eb2[lane&15];
    float4 w30 = *(const float4*)(r3);
    const float w3h = r3[4], eb3 = r3[5];

    s_h1[wv][lane] = 0.f;
    float c1 = 0.f, c2 = 0.f, c3 = 0.f;
    float bc2_0 = 0.f, bc2_1 = 0.f, bc2_2 = 0.f, bc2_3 = 0.f;  // h2[i-2] broadcasts

    float4 pfA = ((const float4*)xbA)[lane];
    float4 pfB = ((const float4*)xbB)[lane];
    float xga[8], xgb[8];

    auto stage_and_xg = [&](int tc){
      ((float4*)&s_x[wv][0])[lane]   = pfA;
      ((float4*)&s_x[wv][256])[lane] = pfB;
      if (tc + 8 < 128){
        pfA = ((const float4*)(xbA + (tc+8)*32))[lane];
        pfB = ((const float4*)(xbB + (tc+8)*32))[lane];
      }
      #pragma unroll
      for (int tt=0; tt<8; ++tt){
        const float4* xA4 = (const float4*)&s_x[wv][tt*32];
        const float4* xB4 = (const float4*)&s_x[wv][256+tt*32];
        float pa0=eb1, pa1=0.f, pa2=0.f, pa3=0.f;
        float pb0=eb1, pb1=0.f, pb2=0.f, pb3=0.f;
        #pragma unroll
        for (int g=0; g<8; ++g){
          float4 w = w1q[g];
          float4 xa = xA4[g], xb = xB4[g];
          pa0 = fmaf(w.x, xa.x, pa0);  pb0 = fmaf(w.x, xb.x, pb0);
          pa1 = fmaf(w.y, xa.y, pa1);  pb1 = fmaf(w.y, xb.y, pb1);
          pa2 = fmaf(w.z, xa.z, pa2);  pb2 = fmaf(w.z, xb.z, pb2);
          pa3 = fmaf(w.w, xa.w, pa3);  pb3 = fmaf(w.w, xb.w, pb3);
        }
        xga[tt] = (pa0+pa1)+(pa2+pa3);
        xgb[tt] = (pb0+pb1)+(pb2+pb3);
      }
    };

    // skewed iteration: {e1(i) if D1, e2(i-1) if D2, e3(i-2) if D3}
    auto enc_iter = [&](int D1_, int D2_, int D3_, float xa, float xb){
      float4 ha0,ha1,ha2,ha3,hb0,hb1,hb2,hb3,qq0,qq1,qq2,qq3;
      float h1new = 0.f, nb0=0.f, nb1=0.f, nb2=0.f, nb3=0.f;
      // ---- reads (all generation i-1, before any write this iteration) ----
      if (D1_){
        const float4* h1A = (const float4*)&s_h1[wv][0];
        const float4* h1B = (const float4*)&s_h1[wv][16];
        ha0=h1A[0]; ha1=h1A[1]; ha2=h1A[2]; ha3=h1A[3];
        hb0=h1B[0]; hb1=h1B[1]; hb2=h1B[2]; hb3=h1B[3];
      }
      if (D2_){
        const float4* h1s = (const float4*)&s_h1[wv][h16];
        qq0=h1s[0]; qq1=h1s[1]; qq2=h1s[2]; qq3=h1s[3];
      }
      // ---- e1(i) ----
      if (D1_){
        float aA0 = xa, aA1=0.f, aA2=0.f, aA3=0.f;
        float aB0 = xb, aB1=0.f, aB2=0.f, aB3=0.f;
        aA0=fmaf(wh1q[0].x,ha0.x,aA0); aB0=fmaf(wh1q[0].x,hb0.x,aB0);
        aA1=fmaf(wh1q[0].y,ha0.y,aA1); aB1=fmaf(wh1q[0].y,hb0.y,aB1);
        aA2=fmaf(wh1q[0].z,ha0.z,aA2); aB2=fmaf(wh1q[0].z,hb0.z,aB2);
        aA3=fmaf(wh1q[0].w,ha0.w,aA3); aB3=fmaf(wh1q[0].w,hb0.w,aB3);
        aA0=fmaf(wh1q[1].x,ha1.x,aA0); aB0=fmaf(wh1q[1].x,hb1.x,aB0);
        aA1=fmaf(wh1q[1].y,ha1.y,aA1); aB1=fmaf(wh1q[1].y,hb1.y,aB1);
        aA2=fmaf(wh1q[1].z,ha1.z,aA2); aB2=fmaf(wh1q[1].z,hb1.z,aB2);
        aA3=fmaf(wh1q[1].w,ha1.w,aA3); aB3=fmaf(wh1q[1].w,hb1.w,aB3);
        aA0=fmaf(wh1q[2].x,ha2.x,aA0); aB0=fmaf(wh1q[2].x,hb2.x,aB0);
        aA1=fmaf(wh1q[2].y,ha2.y,aA1); aB1=fmaf(wh1q[2].y,hb2.y,aB1);
        aA2=fmaf(wh1q[2].z,ha2.z,aA2); aB2=fmaf(wh1q[2].z,hb2.z,aB2);
        aA3=fmaf(wh1q[2].w,ha2.w,aA3); aB3=fmaf(wh1q[2].w,hb2.w,aB3);
        aA0=fmaf(wh1q[3].x,ha3.x,aA0); aB0=fmaf(wh1q[3].x,hb3.x,aB0);
        aA1=fmaf(wh1q[3].y,ha3.y,aA1); aB1=fmaf(wh1q[3].y,hb3.y,aB1);
        aA2=fmaf(wh1q[3].z,ha3.z,aA2); aB2=fmaf(wh1q[3].z,hb3.z,aB2);
        aA3=fmaf(wh1q[3].w,ha3.w,aA3); aB3=fmaf(wh1q[3].w,hb3.w,aB3);
        float vA = fmaf(sigm((aA0+aA1)+(aA2+aA3)), A1, B1);
        float vB = fmaf(sigm((aB0+aB1)+(aB2+aB3)), A1, B1);
        // depth-1 rotations: all three exchanges issue in parallel from v
        float t1A = SWX(16)(vA);
        float t2A = __shfl_xor(vA, 32, 64);
        float t3A = __shfl_xor(vA, 48, 64);
        float t1B = SWX(16)(vB);
        float t2B = __shfl_xor(vB, 32, 64);
        float t3B = __shfl_xor(vB, 48, 64);
        float ip = selA ? vA  : t1B;
        float fp = selA ? t1A : vB;
        float gp = selA ? t2A : t3B;
        float op = selA ? t3A : t2B;
        c1 = fmaf(fp, c1, ip*gp);
        h1new = op * tanh_f(c1);                    // valid lanes 0-31
      }
      // ---- e2(i-1): input h1[i-1] (qq), recurrent h2[i-2] (bc2_*) ----
      if (D2_){
        float a0 = eb2, a1 = 0.f;
        a0 = fmaf(w2q0.x,qq0.x,a0);  a1 = fmaf(w2q0.y,qq0.y,a1);
        a0 = fmaf(w2q0.z,qq0.z,a0);  a1 = fmaf(w2q0.w,qq0.w,a1);
        a0 = fmaf(w2q1.x,qq1.x,a0);  a1 = fmaf(w2q1.y,qq1.y,a1);
        a0 = fmaf(w2q1.z,qq1.z,a0);  a1 = fmaf(w2q1.w,qq1.w,a1);
        a0 = fmaf(w2q2.x,qq2.x,a0);  a1 = fmaf(w2q2.y,qq2.y,a1);
        a0 = fmaf(w2q2.z,qq2.z,a0);  a1 = fmaf(w2q2.w,qq2.w,a1);
        a0 = fmaf(w2q3.x,qq3.x,a0);  a1 = fmaf(w2q3.y,qq3.y,a1);
        a0 = fmaf(w2q3.z,qq3.z,a0);  a1 = fmaf(w2q3.w,qq3.w,a1);
        a0 = fmaf(w2q4.x,bc2_0,a0);  a1 = fmaf(w2q4.y,bc2_1,a1);
        a0 = fmaf(w2q4.z,bc2_2,a0);  a1 = fmaf(w2q4.w,bc2_3,a1);
        float v2 = fmaf(sigm(a0+a1), A2, B2);
        float f2 = SWX(4)(v2), g2 = SWX(8)(v2), o2 = SWX(12)(v2);
        c2 = fmaf(f2, c2, v2*g2);                   // valid lanes 0-3, 16-19
        float h2v = o2 * tanh_f(c2);
        nb0 = BC16(0)(h2v); nb1 = BC16(1)(h2v);
        nb2 = BC16(2)(h2v); nb3 = BC16(3)(h2v);
      }
      // ---- e3(i-2): input h2[i-2] (bc2_* prev), recurrent h3[i-3] (h3b) ----
      if (D3_){
        float a = fmaf(w3h, h3b, eb3);
        a = fmaf(w30.x, bc2_0, a);
        a = fmaf(w30.y, bc2_1, a);
        a = fmaf(w30.z, bc2_2, a);
        a = fmaf(w30.w, bc2_3, a);
        float v3 = fmaf(sigm(a), A3, B3);
        float f3 = SWX(1)(v3), g3 = SWX(2)(v3), o3 = SWX(3)(v3);
        c3 = fmaf(f3, c3, v3*g3);                   // valid lanes 0, 16
        h3b = BC16(0)(o3 * tanh_f(c3));
      }
      // ---- writes ----
      if (D1_) s_h1[wv][lane] = h1new;
      if (D2_){ bc2_0 = nb0; bc2_1 = nb1; bc2_2 = nb2; bc2_3 = nb3; }
    };

    // chunk 0: pipeline fill
    stage_and_xg(0);
    enc_iter(1,0,0, xga[0], xgb[0]);
    enc_iter(1,1,0, xga[1], xgb[1]);
    #pragma unroll
    for (int tt=2; tt<8; ++tt) enc_iter(1,1,1, xga[tt], xgb[tt]);
    // steady chunks
    for (int tc=8; tc<128; tc+=8){
      stage_and_xg(tc);
      #pragma unroll
      for (int tt=0; tt<8; ++tt) enc_iter(1,1,1, xga[tt], xgb[tt]);
    }
    // drain
    enc_iter(0,1,1, 0.f, 0.f);
    enc_iter(0,0,1, 0.f, 0.f);
  }

  // ======================= DECODER =======================
  {
    const float encv = h3b;                          // valid lanes 0-31
    const float p1  = fmaf(rd1[4], encv, rd1[5]);
    const float bd2 = rd2[12];
    const float bd3 = s_d3[(6*64+lane)*4];
    const float bo  = rw[16];
    float4 wd1 = *(const float4*)(rd1);
    float4 w2a = *(const float4*)(rd2);
    float4 w2b = *(const float4*)(rd2+4);
    float4 w2c = *(const float4*)(rd2+8);
    float4 d3q[6];
    #pragma unroll
    for (int g=0; g<6; ++g) d3q[g] = d3v[g*64+lane];
    float4 woa = *(const float4*)(rw);
    float4 wob = *(const float4*)(rw+4);
    float4 woc = *(const float4*)(rw+8);
    float4 wod = *(const float4*)(rw+12);

    s_g1[wv][lane] = 0.f;  s_g2[wv][lane] = 0.f;  s_g3[wv][lane] = 0.f;
    float dc1 = 0.f, dc2 = 0.f, dc3 = 0.f;
    float* __restrict__ obSel = (lane < 32) ? (obA + lane) : (obB + lane - 32);

    // skewed iteration: {d1(i), d2(i-1), d3(i-2), lin+store(i-3)->TO}
    auto dec_iter = [&](int D1_, int D2_, int D3_, int DL_, int TO){
      float4 g1q, g1s, g2a, g2b, p2a0, p2a1, p2b0, p2b1;
      float4 r3a0,r3a1,r3a2,r3a3, r3b0,r3b1,r3b2,r3b3, u0,u1,u2,u3;
      float g1new=0.f, g2new=0.f, g3new=0.f, ovv=0.f;
      if (D1_) g1q = *(const float4*)&s_g1[wv][h16];
      if (D2_){
        g1s = *(const float4*)&s_g1[wv][h32s];
        g2a = *(const float4*)&s_g2[wv][h32];
        g2b = *(const float4*)&s_g2[wv][h32+4];
      }
      if (D3_){
        const float4* g2A = (const float4*)&s_g2[wv][0];
        const float4* g2B = (const float4*)&s_g2[wv][32];
        p2a0=g2A[0]; p2a1=g2A[1]; p2b0=g2B[0]; p2b1=g2B[1];
        const float4* g3A = (const float4*)&s_g3[wv][0];
        const float4* g3B = (const float4*)&s_g3[wv][16];
        r3a0=g3A[0]; r3a1=g3A[1]; r3a2=g3A[2]; r3a3=g3A[3];
        r3b0=g3B[0]; r3b1=g3B[1]; r3b2=g3B[2]; r3b3=g3B[3];
      }
      if (DL_){
        const float4* g3s = (const float4*)&s_g3[wv][h32s];
        u0=g3s[0]; u1=g3s[1]; u2=g3s[2]; u3=g3s[3];
      }
      if (D1_){
        float a0 = p1, a1 = 0.f;
        a0 = fmaf(wd1.x, g1q.x, a0); a1 = fmaf(wd1.y, g1q.y, a1);
        a0 = fmaf(wd1.z, g1q.z, a0); a1 = fmaf(wd1.w, g1q.w, a1);
        float v1 = fmaf(sigm(a0+a1), A2, B2);
        float f1 = SWX(4)(v1), gg1 = SWX(8)(v1), o1 = SWX(12)(v1);
        dc1 = fmaf(f1, dc1, v1*gg1);
        g1new = o1 * tanh_f(dc1);
      }
      if (D2_){
        float a0 = bd2, a1 = 0.f;
        a0 = fmaf(w2a.x, g1s.x, a0); a1 = fmaf(w2a.y, g1s.y, a1);
        a0 = fmaf(w2a.z, g1s.z, a0); a1 = fmaf(w2a.w, g1s.w, a1);
        a0 = fmaf(w2b.x, g2a.x, a0); a1 = fmaf(w2b.y, g2a.y, a1);
        a0 = fmaf(w2b.z, g2a.z, a0); a1 = fmaf(w2b.w, g2a.w, a1);
        a0 = fmaf(w2c.x, g2b.x, a0); a1 = fmaf(w2c.y, g2b.y, a1);
        a0 = fmaf(w2c.z, g2b.z, a0); a1 = fmaf(w2c.w, g2b.w, a1);
        float v2 = fmaf(sigm(a0+a1), AD2, BD2);
        float f2 = SWX(8)(v2), gg2 = SWX(16)(v2), o2 = SWX(24)(v2);
        dc2 = fmaf(f2, dc2, v2*gg2);
        g2new = o2 * tanh_f(dc2);
      }
      if (D3_){
        float aA0=bd3, aA1=0.f, aA2=0.f, aA3=0.f;
        float aB0=bd3, aB1=0.f, aB2=0.f, aB3=0.f;
        aA0=fmaf(d3q[0].x,p2a0.x,aA0); aB0=fmaf(d3q[0].x,p2b0.x,aB0);
        aA1=fmaf(d3q[0].y,p2a0.y,aA1); aB1=fmaf(d3q[0].y,p2b0.y,aB1);
        aA2=fmaf(d3q[0].z,p2a0.z,aA2); aB2=fmaf(d3q[0].z,p2b0.z,aB2);
        aA3=fmaf(d3q[0].w,p2a0.w,aA3); aB3=fmaf(d3q[0].w,p2b0.w,aB3);
        aA0=fmaf(d3q[1].x,p2a1.x,aA0); aB0=fmaf(d3q[1].x,p2b1.x,aB0);
        aA1=fmaf(d3q[1].y,p2a1.y,aA1); aB1=fmaf(d3q[1].y,p2b1.y,aB1);
        aA2=fmaf(d3q[1].z,p2a1.z,aA2); aB2=fmaf(d3q[1].z,p2b1.z,aB2);
        aA3=fmaf(d3q[1].w,p2a1.w,aA3); aB3=fmaf(d3q[1].w,p2b1.w,aB3);
        aA0=fmaf(d3q[2].x,r3a0.x,aA0); aB0=fmaf(d3q[2].x,r3b0.x,aB0);
        aA1=fmaf(d3q[2].y,r3a0.y,aA1); aB1=fmaf(d3q[2].y,r3b0.y,aB1);
        aA2=fmaf(d3q[2].z,r3a0.z,aA2); aB2=fmaf(d3q[2].z,r3b0.z,aB2);
        aA3=fmaf(d3q[2].w,r3a0.w,aA3); aB3=fmaf(d3q[2].w,r3b0.w,aB3);
        aA0=fmaf(d3q[3].x,r3a1.x,aA0); aB0=fmaf(d3q[3].x,r3b1.x,aB0);
        aA1=fmaf(d3q[3].y,r3a1.y,aA1); aB1=fmaf(d3q[3].y,r3b1.y,aB1);
        aA2=fmaf(d3q[3].z,r3a1.z,aA2); aB2=fmaf(d3q[3].z,r3b1.z,aB2);
        aA3=fmaf(d3q[3].w,r3a1.w,aA3); aB3=fmaf(d3q[3].w,r3b1.w,aB3);
        aA0=fmaf(d3q[4].x,r3a2.x,aA0); aB0=fmaf(d3q[4].x,r3b2.x,aB0);
        aA1=fmaf(d3q[4].y,r3a2.y,aA1); aB1=fmaf(d3q[4].y,r3b2.y,aB1);
        aA2=fmaf(d3q[4].z,r3a2.z,aA2); aB2=fmaf(d3q[4].z,r3b2.z,aB2);
        aA3=fmaf(d3q[4].w,r3a2.w,aA3); aB3=fmaf(d3q[4].w,r3b2.w,aB3);
        aA0=fmaf(d3q[5].x,r3a3.x,aA0); aB0=fmaf(d3q[5].x,r3b3.x,aB0);
        aA1=fmaf(d3q[5].y,r3a3.y,aA1); aB1=fmaf(d3q[5].y,r3b3.y,aB1);
        aA2=fmaf(d3q[5].z,r3a3.z,aA2); aB2=fmaf(d3q[5].z,r3b3.z,aB2);
        aA3=fmaf(d3q[5].w,r3a3.w,aA3); aB3=fmaf(d3q[5].w,r3b3.w,aB3);
        float vA = fmaf(sigm((aA0+aA1)+(aA2+aA3)), A1, B1);
        float vB = fmaf(sigm((aB0+aB1)+(aB2+aB3)), A1, B1);
        float t1A = SWX(16)(vA);
        float t2A = __shfl_xor(vA, 32, 64);
        float t3A = __shfl_xor(vA, 48, 64);
        float t1B = SWX(16)(vB);
        float t2B = __shfl_xor(vB, 32, 64);
        float t3B = __shfl_xor(vB, 48, 64);
        float ip = selA ? vA  : t1B;
        float fp = selA ? t1A : vB;
        float gp = selA ? t2A : t3B;
        float op = selA ? t3A : t2B;
        dc3 = fmaf(fp, dc3, ip*gp);
        g3new = op * tanh_f(dc3);
      }
      if (DL_){
        float ov0 = bo, ov1 = 0.f;
        ov0 = fmaf(woa.x, u0.x, ov0);  ov1 = fmaf(woa.y, u0.y, ov1);
        ov0 = fmaf(woa.z, u0.z, ov0);  ov1 = fmaf(woa.w, u0.w, ov1);
        ov0 = fmaf(wob.x, u1.x, ov0);  ov1 = fmaf(wob.y, u1.y, ov1);
        ov0 = fmaf(wob.z, u1.z, ov0);  ov1 = fmaf(wob.w, u1.w, ov1);
        ov0 = fmaf(woc.x, u2.x, ov0);  ov1 = fmaf(woc.y, u2.y, ov1);
        ov0 = fmaf(woc.z, u2.z, ov0);  ov1 = fmaf(woc.w, u2.w, ov1);
        ov0 = fmaf(wod.x, u3.x, ov0);  ov1 = fmaf(wod.y, u3.y, ov1);
        ov0 = fmaf(wod.z, u3.z, ov0);  ov1 = fmaf(wod.w, u3.w, ov1);
        ovv = ov0 + ov1;
      }
      if (D1_) s_g1[wv][lane] = g1new;
      if (D2_) s_g2[wv][lane] = g2new;
      if (D3_) s_g3[wv][lane] = g3new;
      if (DL_) obSel[TO*32] = ovv;
    };

    dec_iter(1,0,0,0, 0);
    dec_iter(1,1,0,0, 0);
    dec_iter(1,1,1,0, 0);
    #pragma unroll 2
    for (int i=3; i<128; ++i) dec_iter(1,1,1,1, i-3);
    dec_iter(0,1,1,1, 125);
    dec_iter(0,0,1,1, 126);
    dec_iter(0,0,0,1, 127);
  }
}

extern "C" void kernel_launch(void* const* d_in, const int* in_sizes, int n_in,
                              void* d_out, int out_size, void* d_ws, size_t ws_size,
                              hipStream_t stream) {
  (void)in_sizes; (void)n_in; (void)d_ws; (void)ws_size; (void)out_size;
  const float* x    = (const float*)d_in[0];
  const float* e1Wi = (const float*)d_in[1];
  const float* e1Wh = (const float*)d_in[2];
  const float* e1bi = (const float*)d_in[3];
  const float* e1bh = (const float*)d_in[4];
  const float* e2Wi = (const float*)d_in[5];
  const float* e2Wh = (const float*)d_in[6];
  const float* e2bi = (const float*)d_in[7];
  const float* e2bh = (const float*)d_in[8];
  const float* e3Wi = (const float*)d_in[9];
  const float* e3Wh = (const float*)d_in[10];
  const float* e3bi = (const float*)d_in[11];
  const float* e3bh = (const float*)d_in[12];
  const float* d1Wi = (const float*)d_in[13];
  const float* d1Wh = (const float*)d_in[14];
  const float* d1bi = (const float*)d_in[15];
  const float* d1bh = (const float*)d_in[16];
  const float* d2Wi = (const float*)d_in[17];
  const float* d2Wh = (const float*)d_in[18];
  const float* d2bi = (const float*)d_in[19];
  const float* d2bh = (const float*)d_in[20];
  const float* d3Wi = (const float*)d_in[21];
  const float* d3Wh = (const float*)d_in[22];
  const float* d3bi = (const float*)d_in[23];
  const float* d3bh = (const float*)d_in[24];
  const float* Wout = (const float*)d_in[25];
  const float* boutp= (const float*)d_in[26];
  float* out = (float*)d_out;

  lstm_ae_fused<<<512, 256, 0, stream>>>(x,
      e1Wi, e1Wh, e1bi, e1bh,
      e2Wi, e2Wh, e2bi, e2bh,
      e3Wi, e3Wh, e3bi, e3bh,
      d1Wi, d1Wh, d1bi, d1bh,
      d2Wi, d2Wh, d2bi, d2bh,
      d3Wi, d3Wh, d3bi, d3bh,
      Wout, boutp, out);
}

// Round 12
// 196.216 us; speedup vs baseline: 1.8218x; 1.8218x over previous
//
#include <hip/hip_runtime.h>

#define LOG2E 1.44269504088896340736f

__device__ __forceinline__ float vexp2(float x){ float r; asm("v_exp_f32 %0, %1" : "=v"(r) : "v"(x)); return r; }
__device__ __forceinline__ float vrcp (float x){ float r; asm("v_rcp_f32 %0, %1" : "=v"(r) : "v"(x)); return r; }
template<int OFF> __device__ __forceinline__ float dsw(float v){
  return __int_as_float(__builtin_amdgcn_ds_swizzle(__float_as_int(v), OFF));
}
// xor-exchange within 32-group (and=0x1F)
#define SWX(m)  dsw<((m)<<10)|0x1F>
// broadcast slot k of own 16-half within the 32-group: src = (lane&16)|k
#define BC16(k) dsw<((k)<<5)|0x10>
__device__ __forceinline__ float sigm(float x){ return vrcp(1.0f + vexp2(x * (-LOG2E))); }
__device__ __forceinline__ float tanh_f(float x){
  float s = vrcp(1.0f + vexp2(x * (-2.0f*LOG2E)));
  return s + s - 1.0f;
}

// Layer-skewed software pipeline: iteration i computes {e1(i), e2(i-1), e3(i-2)}
// (decoder: {d1(i), d2(i-1), d3(i-2), lin(i-3)}). Stages depend only on
// previous-iteration state, so their latency chains interleave.
// launch_bounds(256, 2): 2nd arg is MIN WAVES PER EU; for 256-thread blocks it
// equals blocks/CU. 2 -> VGPR cap 128 (the occupancy cliff edge, measured
// R7/R10/R11: >128 VGPR -> 1 block/CU; cap 64 (R11, arg=4) -> scratch spills).
__global__ void __launch_bounds__(256, 2)
lstm_ae_fused(const float* __restrict__ x,
              const float* __restrict__ e1Wi, const float* __restrict__ e1Wh, const float* __restrict__ e1bi, const float* __restrict__ e1bh,
              const float* __restrict__ e2Wi, const float* __restrict__ e2Wh, const float* __restrict__ e2bi, const float* __restrict__ e2bh,
              const float* __restrict__ e3Wi, const float* __restrict__ e3Wh, const float* __restrict__ e3bi, const float* __restrict__ e3bh,
              const float* __restrict__ d1Wi, const float* __restrict__ d1Wh, const float* __restrict__ d1bi, const float* __restrict__ d1bh,
              const float* __restrict__ d2Wi, const float* __restrict__ d2Wh, const float* __restrict__ d2bi, const float* __restrict__ d2bh,
              const float* __restrict__ d3Wi, const float* __restrict__ d3Wh, const float* __restrict__ d3bi, const float* __restrict__ d3bh,
              const float* __restrict__ Wout, const float* __restrict__ bout,
              float* __restrict__ out)
{
  const int tid  = threadIdx.x;
  const int lane = tid & 63;
  const int wv   = tid >> 6;                 // wave 0..3
  const int gw   = blockIdx.x*4 + wv;        // global wave
  const int bA   = gw*2, bB = gw*2 + 1;
  const float* __restrict__ xbA = x + (size_t)bA * 4096;
  const float* __restrict__ xbB = x + (size_t)bB * 4096;
  float* __restrict__ obA = out + (size_t)bA * 4096;
  float* __restrict__ obB = out + (size_t)bB * 4096;

  // ---------------- LDS (39936 B -> 2 blocks/CU) ----------------
  __shared__ float s_e1[13*64*4];   // per-lane quads: 0-7 w1i, 8-11 w1h, 12.x eb1
  __shared__ float s_e2[16*20];
  __shared__ float s_eb2[16];
  __shared__ float s_e3[4*8];
  __shared__ float s_d1[16*8];
  __shared__ float s_d2[32*20];
  __shared__ float s_d3[7*64*4];    // 0-1 wd3i, 2-5 wd3h, 6.x bd3
  __shared__ float s_wo[32*20];
  __shared__ float s_x [4][512];    // per wave: [0..255] A 8-step chunk, [256..511] B
  __shared__ float s_h1[4][64];     // e1 h state: A 0-15, B 16-31
  __shared__ float s_g1[4][64];     // decoder hd1
  __shared__ float s_g2[4][64];     // decoder hd2
  __shared__ float s_g3[4][64];     // decoder hd3

  // ---------------- one-time weight staging (g-gate rows pre-scaled x2) ----------------
  if (tid < 64){
    const int l = tid;
    const float A1l = (l>=32 && l<48) ? 2.f : 1.f;
    for (int k=0;k<32;++k) s_e1[((k>>2)*64+l)*4+(k&3)]      = e1Wi[l*32+k]*A1l;
    for (int k=0;k<16;++k) s_e1[(((k>>2)+8)*64+l)*4+(k&3)]  = e1Wh[l*16+k]*A1l;
    s_e1[(12*64+l)*4] = (e1bi[l]+e1bh[l])*A1l;
    for (int k=0;k<8;++k)  s_d3[((k>>2)*64+l)*4+(k&3)]      = d3Wi[l*8+k]*A1l;
    for (int k=0;k<16;++k) s_d3[(((k>>2)+2)*64+l)*4+(k&3)]  = d3Wh[l*16+k]*A1l;
    s_d3[(6*64+l)*4] = (d3bi[l]+d3bh[l])*A1l;
    if (l < 16){
      const float A2l = (l>=8 && l<12) ? 2.f : 1.f;
      for (int k=0;k<16;++k) s_e2[l*20+k]    = e2Wi[l*16+k]*A2l;
      for (int k=0;k<4;++k)  s_e2[l*20+16+k] = e2Wh[l*4+k]*A2l;
      s_eb2[l] = (e2bi[l]+e2bh[l])*A2l;
      for (int k=0;k<4;++k)  s_d1[l*8+k] = d1Wh[l*4+k]*A2l;
      s_d1[l*8+4] = d1Wi[l]*A2l;
      s_d1[l*8+5] = (d1bi[l]+d1bh[l])*A2l;
    }
    if (l < 4){
      const float A3l = (l==2) ? 2.f : 1.f;
      for (int k=0;k<4;++k) s_e3[l*8+k] = e3Wi[l*4+k]*A3l;
      s_e3[l*8+4] = e3Wh[l]*A3l;
      s_e3[l*8+5] = (e3bi[l]+e3bh[l])*A3l;
    }
    if (l < 32){
      const float AD2l = (l>=16 && l<24) ? 2.f : 1.f;
      for (int k=0;k<4;++k) s_d2[l*20+k]   = d2Wi[l*4+k]*AD2l;
      for (int k=0;k<8;++k) s_d2[l*20+4+k] = d2Wh[l*8+k]*AD2l;
      s_d2[l*20+12] = (d2bi[l]+d2bh[l])*AD2l;
      for (int k=0;k<16;++k) s_wo[l*20+k] = Wout[l*16+k];
      s_wo[l*20+16] = bout[l];
    }
  }
  __syncthreads();

  const bool isg1 = (lane >= 32) && (lane < 48);
  const bool isg2 = ((lane & 15) >= 8) && ((lane & 15) < 12);
  const bool isg3 = ((lane & 3) == 2);
  const bool isgD2= ((lane & 31) >= 16) && ((lane & 31) < 24);
  const float A1 = isg1 ? 2.f : 1.f,  B1 = isg1 ? -1.f : 0.f;
  const float A2 = isg2 ? 2.f : 1.f,  B2 = isg2 ? -1.f : 0.f;
  const float A3 = isg3 ? 2.f : 1.f,  B3 = isg3 ? -1.f : 0.f;
  const float AD2= isgD2? 2.f : 1.f,  BD2= isgD2? -1.f : 0.f;
  const bool selA = ((lane & 16) == 0);
  const int  h16  = lane & 16;
  const int  h32  = lane & 32;
  const int  h32s = (lane & 32) >> 1;

  const float4* e1v = (const float4*)s_e1;
  const float4* d3v = (const float4*)s_d3;
  const float* r2  = &s_e2[(lane&15)*20];
  const float* r3  = &s_e3[(lane&3)*8];
  const float* rd1 = &s_d1[(lane&15)*8];
  const float* rd2 = &s_d2[(lane&31)*20];
  const float* rw  = &s_wo[(lane&31)*20];

  float h3b = 0.f;   // survives into decoder (enc)

  // ======================= ENCODER =======================
  {
    float4 w1q[8], wh1q[4];
    #pragma unroll
    for (int g=0; g<8; ++g) w1q[g] = e1v[g*64+lane];
    #pragma unroll
    for (int g=0; g<4; ++g) wh1q[g] = e1v[(8+g)*64+lane];
    const float eb1 = s_e1[(12*64+lane)*4];
    float4 w2q0 = *(const float4*)(r2);
    float4 w2q1 = *(const float4*)(r2+4);
    float4 w2q2 = *(const float4*)(r2+8);
    float4 w2q3 = *(const float4*)(r2+12);
    float4 w2q4 = *(const float4*)(r2+16);
    const float eb2 = s_eb2[lane&15];
    float4 w30 = *(const float4*)(r3);
    const float w3h = r3[4], eb3 = r3[5];

    s_h1[wv][lane] = 0.f;
    float c1 = 0.f, c2 = 0.f, c3 = 0.f;
    float bc2_0 = 0.f, bc2_1 = 0.f, bc2_2 = 0.f, bc2_3 = 0.f;  // h2[i-2] broadcasts

    float4 pfA = ((const float4*)xbA)[lane];
    float4 pfB = ((const float4*)xbB)[lane];
    float xga[8], xgb[8];

    auto stage_and_xg = [&](int tc){
      ((float4*)&s_x[wv][0])[lane]   = pfA;
      ((float4*)&s_x[wv][256])[lane] = pfB;
      if (tc + 8 < 128){
        pfA = ((const float4*)(xbA + (tc+8)*32))[lane];
        pfB = ((const float4*)(xbB + (tc+8)*32))[lane];
      }
      #pragma unroll
      for (int tt=0; tt<8; ++tt){
        const float4* xA4 = (const float4*)&s_x[wv][tt*32];
        const float4* xB4 = (const float4*)&s_x[wv][256+tt*32];
        float pa0=eb1, pa1=0.f, pa2=0.f, pa3=0.f;
        float pb0=eb1, pb1=0.f, pb2=0.f, pb3=0.f;
        #pragma unroll
        for (int g=0; g<8; ++g){
          float4 w = w1q[g];
          float4 xa = xA4[g], xb = xB4[g];
          pa0 = fmaf(w.x, xa.x, pa0);  pb0 = fmaf(w.x, xb.x, pb0);
          pa1 = fmaf(w.y, xa.y, pa1);  pb1 = fmaf(w.y, xb.y, pb1);
          pa2 = fmaf(w.z, xa.z, pa2);  pb2 = fmaf(w.z, xb.z, pb2);
          pa3 = fmaf(w.w, xa.w, pa3);  pb3 = fmaf(w.w, xb.w, pb3);
        }
        xga[tt] = (pa0+pa1)+(pa2+pa3);
        xgb[tt] = (pb0+pb1)+(pb2+pb3);
      }
    };

    // skewed iteration: {e1(i) if D1, e2(i-1) if D2, e3(i-2) if D3}
    auto enc_iter = [&](int D1_, int D2_, int D3_, float xa, float xb){
      float4 ha0,ha1,ha2,ha3,hb0,hb1,hb2,hb3,qq0,qq1,qq2,qq3;
      float h1new = 0.f, nb0=0.f, nb1=0.f, nb2=0.f, nb3=0.f;
      // ---- reads (all generation i-1, before any write this iteration) ----
      if (D1_){
        const float4* h1A = (const float4*)&s_h1[wv][0];
        const float4* h1B = (const float4*)&s_h1[wv][16];
        ha0=h1A[0]; ha1=h1A[1]; ha2=h1A[2]; ha3=h1A[3];
        hb0=h1B[0]; hb1=h1B[1]; hb2=h1B[2]; hb3=h1B[3];
      }
      if (D2_){
        const float4* h1s = (const float4*)&s_h1[wv][h16];
        qq0=h1s[0]; qq1=h1s[1]; qq2=h1s[2]; qq3=h1s[3];
      }
      // ---- e1(i) ----
      if (D1_){
        float aA0 = xa, aA1=0.f, aA2=0.f, aA3=0.f;
        float aB0 = xb, aB1=0.f, aB2=0.f, aB3=0.f;
        aA0=fmaf(wh1q[0].x,ha0.x,aA0); aB0=fmaf(wh1q[0].x,hb0.x,aB0);
        aA1=fmaf(wh1q[0].y,ha0.y,aA1); aB1=fmaf(wh1q[0].y,hb0.y,aB1);
        aA2=fmaf(wh1q[0].z,ha0.z,aA2); aB2=fmaf(wh1q[0].z,hb0.z,aB2);
        aA3=fmaf(wh1q[0].w,ha0.w,aA3); aB3=fmaf(wh1q[0].w,hb0.w,aB3);
        aA0=fmaf(wh1q[1].x,ha1.x,aA0); aB0=fmaf(wh1q[1].x,hb1.x,aB0);
        aA1=fmaf(wh1q[1].y,ha1.y,aA1); aB1=fmaf(wh1q[1].y,hb1.y,aB1);
        aA2=fmaf(wh1q[1].z,ha1.z,aA2); aB2=fmaf(wh1q[1].z,hb1.z,aB2);
        aA3=fmaf(wh1q[1].w,ha1.w,aA3); aB3=fmaf(wh1q[1].w,hb1.w,aB3);
        aA0=fmaf(wh1q[2].x,ha2.x,aA0); aB0=fmaf(wh1q[2].x,hb2.x,aB0);
        aA1=fmaf(wh1q[2].y,ha2.y,aA1); aB1=fmaf(wh1q[2].y,hb2.y,aB1);
        aA2=fmaf(wh1q[2].z,ha2.z,aA2); aB2=fmaf(wh1q[2].z,hb2.z,aB2);
        aA3=fmaf(wh1q[2].w,ha2.w,aA3); aB3=fmaf(wh1q[2].w,hb2.w,aB3);
        aA0=fmaf(wh1q[3].x,ha3.x,aA0); aB0=fmaf(wh1q[3].x,hb3.x,aB0);
        aA1=fmaf(wh1q[3].y,ha3.y,aA1); aB1=fmaf(wh1q[3].y,hb3.y,aB1);
        aA2=fmaf(wh1q[3].z,ha3.z,aA2); aB2=fmaf(wh1q[3].z,hb3.z,aB2);
        aA3=fmaf(wh1q[3].w,ha3.w,aA3); aB3=fmaf(wh1q[3].w,hb3.w,aB3);
        float vA = fmaf(sigm((aA0+aA1)+(aA2+aA3)), A1, B1);
        float vB = fmaf(sigm((aB0+aB1)+(aB2+aB3)), A1, B1);
        // depth-1 rotations: all three exchanges issue in parallel from v
        float t1A = SWX(16)(vA);
        float t2A = __shfl_xor(vA, 32, 64);
        float t3A = __shfl_xor(vA, 48, 64);
        float t1B = SWX(16)(vB);
        float t2B = __shfl_xor(vB, 32, 64);
        float t3B = __shfl_xor(vB, 48, 64);
        float ip = selA ? vA  : t1B;
        float fp = selA ? t1A : vB;
        float gp = selA ? t2A : t3B;
        float op = selA ? t3A : t2B;
        c1 = fmaf(fp, c1, ip*gp);
        h1new = op * tanh_f(c1);                    // valid lanes 0-31
      }
      // ---- e2(i-1): input h1[i-1] (qq), recurrent h2[i-2] (bc2_*) ----
      if (D2_){
        float a0 = eb2, a1 = 0.f;
        a0 = fmaf(w2q0.x,qq0.x,a0);  a1 = fmaf(w2q0.y,qq0.y,a1);
        a0 = fmaf(w2q0.z,qq0.z,a0);  a1 = fmaf(w2q0.w,qq0.w,a1);
        a0 = fmaf(w2q1.x,qq1.x,a0);  a1 = fmaf(w2q1.y,qq1.y,a1);
        a0 = fmaf(w2q1.z,qq1.z,a0);  a1 = fmaf(w2q1.w,qq1.w,a1);
        a0 = fmaf(w2q2.x,qq2.x,a0);  a1 = fmaf(w2q2.y,qq2.y,a1);
        a0 = fmaf(w2q2.z,qq2.z,a0);  a1 = fmaf(w2q2.w,qq2.w,a1);
        a0 = fmaf(w2q3.x,qq3.x,a0);  a1 = fmaf(w2q3.y,qq3.y,a1);
        a0 = fmaf(w2q3.z,qq3.z,a0);  a1 = fmaf(w2q3.w,qq3.w,a1);
        a0 = fmaf(w2q4.x,bc2_0,a0);  a1 = fmaf(w2q4.y,bc2_1,a1);
        a0 = fmaf(w2q4.z,bc2_2,a0);  a1 = fmaf(w2q4.w,bc2_3,a1);
        float v2 = fmaf(sigm(a0+a1), A2, B2);
        float f2 = SWX(4)(v2), g2 = SWX(8)(v2), o2 = SWX(12)(v2);
        c2 = fmaf(f2, c2, v2*g2);                   // valid lanes 0-3, 16-19
        float h2v = o2 * tanh_f(c2);
        nb0 = BC16(0)(h2v); nb1 = BC16(1)(h2v);
        nb2 = BC16(2)(h2v); nb3 = BC16(3)(h2v);
      }
      // ---- e3(i-2): input h2[i-2] (bc2_* prev), recurrent h3[i-3] (h3b) ----
      if (D3_){
        float a = fmaf(w3h, h3b, eb3);
        a = fmaf(w30.x, bc2_0, a);
        a = fmaf(w30.y, bc2_1, a);
        a = fmaf(w30.z, bc2_2, a);
        a = fmaf(w30.w, bc2_3, a);
        float v3 = fmaf(sigm(a), A3, B3);
        float f3 = SWX(1)(v3), g3 = SWX(2)(v3), o3 = SWX(3)(v3);
        c3 = fmaf(f3, c3, v3*g3);                   // valid lanes 0, 16
        h3b = BC16(0)(o3 * tanh_f(c3));
      }
      // ---- writes ----
      if (D1_) s_h1[wv][lane] = h1new;
      if (D2_){ bc2_0 = nb0; bc2_1 = nb1; bc2_2 = nb2; bc2_3 = nb3; }
    };

    // chunk 0: pipeline fill
    stage_and_xg(0);
    enc_iter(1,0,0, xga[0], xgb[0]);
    enc_iter(1,1,0, xga[1], xgb[1]);
    #pragma unroll
    for (int tt=2; tt<8; ++tt) enc_iter(1,1,1, xga[tt], xgb[tt]);
    // steady chunks
    for (int tc=8; tc<128; tc+=8){
      stage_and_xg(tc);
      #pragma unroll
      for (int tt=0; tt<8; ++tt) enc_iter(1,1,1, xga[tt], xgb[tt]);
    }
    // drain
    enc_iter(0,1,1, 0.f, 0.f);
    enc_iter(0,0,1, 0.f, 0.f);
  }

  // ======================= DECODER =======================
  {
    const float encv = h3b;                          // valid lanes 0-31
    const float p1  = fmaf(rd1[4], encv, rd1[5]);
    const float bd2 = rd2[12];
    const float bd3 = s_d3[(6*64+lane)*4];
    const float bo  = rw[16];
    float4 wd1 = *(const float4*)(rd1);
    float4 w2a = *(const float4*)(rd2);
    float4 w2b = *(const float4*)(rd2+4);
    float4 w2c = *(const float4*)(rd2+8);
    float4 d3q[6];
    #pragma unroll
    for (int g=0; g<6; ++g) d3q[g] = d3v[g*64+lane];
    float4 woa = *(const float4*)(rw);
    float4 wob = *(const float4*)(rw+4);
    float4 woc = *(const float4*)(rw+8);
    float4 wod = *(const float4*)(rw+12);

    s_g1[wv][lane] = 0.f;  s_g2[wv][lane] = 0.f;  s_g3[wv][lane] = 0.f;
    float dc1 = 0.f, dc2 = 0.f, dc3 = 0.f;
    float* __restrict__ obSel = (lane < 32) ? (obA + lane) : (obB + lane - 32);

    // skewed iteration: {d1(i), d2(i-1), d3(i-2), lin+store(i-3)->TO}
    auto dec_iter = [&](int D1_, int D2_, int D3_, int DL_, int TO){
      float4 g1q, g1s, g2a, g2b, p2a0, p2a1, p2b0, p2b1;
      float4 r3a0,r3a1,r3a2,r3a3, r3b0,r3b1,r3b2,r3b3, u0,u1,u2,u3;
      float g1new=0.f, g2new=0.f, g3new=0.f, ovv=0.f;
      if (D1_) g1q = *(const float4*)&s_g1[wv][h16];
      if (D2_){
        g1s = *(const float4*)&s_g1[wv][h32s];
        g2a = *(const float4*)&s_g2[wv][h32];
        g2b = *(const float4*)&s_g2[wv][h32+4];
      }
      if (D3_){
        const float4* g2A = (const float4*)&s_g2[wv][0];
        const float4* g2B = (const float4*)&s_g2[wv][32];
        p2a0=g2A[0]; p2a1=g2A[1]; p2b0=g2B[0]; p2b1=g2B[1];
        const float4* g3A = (const float4*)&s_g3[wv][0];
        const float4* g3B = (const float4*)&s_g3[wv][16];
        r3a0=g3A[0]; r3a1=g3A[1]; r3a2=g3A[2]; r3a3=g3A[3];
        r3b0=g3B[0]; r3b1=g3B[1]; r3b2=g3B[2]; r3b3=g3B[3];
      }
      if (DL_){
        const float4* g3s = (const float4*)&s_g3[wv][h32s];
        u0=g3s[0]; u1=g3s[1]; u2=g3s[2]; u3=g3s[3];
      }
      if (D1_){
        float a0 = p1, a1 = 0.f;
        a0 = fmaf(wd1.x, g1q.x, a0); a1 = fmaf(wd1.y, g1q.y, a1);
        a0 = fmaf(wd1.z, g1q.z, a0); a1 = fmaf(wd1.w, g1q.w, a1);
        float v1 = fmaf(sigm(a0+a1), A2, B2);
        float f1 = SWX(4)(v1), gg1 = SWX(8)(v1), o1 = SWX(12)(v1);
        dc1 = fmaf(f1, dc1, v1*gg1);
        g1new = o1 * tanh_f(dc1);
      }
      if (D2_){
        float a0 = bd2, a1 = 0.f;
        a0 = fmaf(w2a.x, g1s.x, a0); a1 = fmaf(w2a.y, g1s.y, a1);
        a0 = fmaf(w2a.z, g1s.z, a0); a1 = fmaf(w2a.w, g1s.w, a1);
        a0 = fmaf(w2b.x, g2a.x, a0); a1 = fmaf(w2b.y, g2a.y, a1);
        a0 = fmaf(w2b.z, g2a.z, a0); a1 = fmaf(w2b.w, g2a.w, a1);
        a0 = fmaf(w2c.x, g2b.x, a0); a1 = fmaf(w2c.y, g2b.y, a1);
        a0 = fmaf(w2c.z, g2b.z, a0); a1 = fmaf(w2c.w, g2b.w, a1);
        float v2 = fmaf(sigm(a0+a1), AD2, BD2);
        float f2 = SWX(8)(v2), gg2 = SWX(16)(v2), o2 = SWX(24)(v2);
        dc2 = fmaf(f2, dc2, v2*gg2);
        g2new = o2 * tanh_f(dc2);
      }
      if (D3_){
        float aA0=bd3, aA1=0.f, aA2=0.f, aA3=0.f;
        float aB0=bd3, aB1=0.f, aB2=0.f, aB3=0.f;
        aA0=fmaf(d3q[0].x,p2a0.x,aA0); aB0=fmaf(d3q[0].x,p2b0.x,aB0);
        aA1=fmaf(d3q[0].y,p2a0.y,aA1); aB1=fmaf(d3q[0].y,p2b0.y,aB1);
        aA2=fmaf(d3q[0].z,p2a0.z,aA2); aB2=fmaf(d3q[0].z,p2b0.z,aB2);
        aA3=fmaf(d3q[0].w,p2a0.w,aA3); aB3=fmaf(d3q[0].w,p2b0.w,aB3);
        aA0=fmaf(d3q[1].x,p2a1.x,aA0); aB0=fmaf(d3q[1].x,p2b1.x,aB0);
        aA1=fmaf(d3q[1].y,p2a1.y,aA1); aB1=fmaf(d3q[1].y,p2b1.y,aB1);
        aA2=fmaf(d3q[1].z,p2a1.z,aA2); aB2=fmaf(d3q[1].z,p2b1.z,aB2);
        aA3=fmaf(d3q[1].w,p2a1.w,aA3); aB3=fmaf(d3q[1].w,p2b1.w,aB3);
        aA0=fmaf(d3q[2].x,r3a0.x,aA0); aB0=fmaf(d3q[2].x,r3b0.x,aB0);
        aA1=fmaf(d3q[2].y,r3a0.y,aA1); aB1=fmaf(d3q[2].y,r3b0.y,aB1);
        aA2=fmaf(d3q[2].z,r3a0.z,aA2); aB2=fmaf(d3q[2].z,r3b0.z,aB2);
        aA3=fmaf(d3q[2].w,r3a0.w,aA3); aB3=fmaf(d3q[2].w,r3b0.w,aB3);
        aA0=fmaf(d3q[3].x,r3a1.x,aA0); aB0=fmaf(d3q[3].x,r3b1.x,aB0);
        aA1=fmaf(d3q[3].y,r3a1.y,aA1); aB1=fmaf(d3q[3].y,r3b1.y,aB1);
        aA2=fmaf(d3q[3].z,r3a1.z,aA2); aB2=fmaf(d3q[3].z,r3b1.z,aB2);
        aA3=fmaf(d3q[3].w,r3a1.w,aA3); aB3=fmaf(d3q[3].w,r3b1.w,aB3);
        aA0=fmaf(d3q[4].x,r3a2.x,aA0); aB0=fmaf(d3q[4].x,r3b2.x,aB0);
        aA1=fmaf(d3q[4].y,r3a2.y,aA1); aB1=fmaf(d3q[4].y,r3b2.y,aB1);
        aA2=fmaf(d3q[4].z,r3a2.z,aA2); aB2=fmaf(d3q[4].z,r3b2.z,aB2);
        aA3=fmaf(d3q[4].w,r3a2.w,aA3); aB3=fmaf(d3q[4].w,r3b2.w,aB3);
        aA0=fmaf(d3q[5].x,r3a3.x,aA0); aB0=fmaf(d3q[5].x,r3b3.x,aB0);
        aA1=fmaf(d3q[5].y,r3a3.y,aA1); aB1=fmaf(d3q[5].y,r3b3.y,aB1);
        aA2=fmaf(d3q[5].z,r3a3.z,aA2); aB2=fmaf(d3q[5].z,r3b3.z,aB2);
        aA3=fmaf(d3q[5].w,r3a3.w,aA3); aB3=fmaf(d3q[5].w,r3b3.w,aB3);
        float vA = fmaf(sigm((aA0+aA1)+(aA2+aA3)), A1, B1);
        float vB = fmaf(sigm((aB0+aB1)+(aB2+aB3)), A1, B1);
        float t1A = SWX(16)(vA);
        float t2A = __shfl_xor(vA, 32, 64);
        float t3A = __shfl_xor(vA, 48, 64);
        float t1B = SWX(16)(vB);
        float t2B = __shfl_xor(vB, 32, 64);
        float t3B = __shfl_xor(vB, 48, 64);
        float ip = selA ? vA  : t1B;
        float fp = selA ? t1A : vB;
        float gp = selA ? t2A : t3B;
        float op = selA ? t3A : t2B;
        dc3 = fmaf(fp, dc3, ip*gp);
        g3new = op * tanh_f(dc3);
      }
      if (DL_){
        float ov0 = bo, ov1 = 0.f;
        ov0 = fmaf(woa.x, u0.x, ov0);  ov1 = fmaf(woa.y, u0.y, ov1);
        ov0 = fmaf(woa.z, u0.z, ov0);  ov1 = fmaf(woa.w, u0.w, ov1);
        ov0 = fmaf(wob.x, u1.x, ov0);  ov1 = fmaf(wob.y, u1.y, ov1);
        ov0 = fmaf(wob.z, u1.z, ov0);  ov1 = fmaf(wob.w, u1.w, ov1);
        ov0 = fmaf(woc.x, u2.x, ov0);  ov1 = fmaf(woc.y, u2.y, ov1);
        ov0 = fmaf(woc.z, u2.z, ov0);  ov1 = fmaf(woc.w, u2.w, ov1);
        ov0 = fmaf(wod.x, u3.x, ov0);  ov1 = fmaf(wod.y, u3.y, ov1);
        ov0 = fmaf(wod.z, u3.z, ov0);  ov1 = fmaf(wod.w, u3.w, ov1);
        ovv = ov0 + ov1;
      }
      if (D1_) s_g1[wv][lane] = g1new;
      if (D2_) s_g2[wv][lane] = g2new;
      if (D3_) s_g3[wv][lane] = g3new;
      if (DL_) obSel[TO*32] = ovv;
    };

    dec_iter(1,0,0,0, 0);
    dec_iter(1,1,0,0, 0);
    dec_iter(1,1,1,0, 0);
    #pragma unroll 2
    for (int i=3; i<128; ++i) dec_iter(1,1,1,1, i-3);
    dec_iter(0,1,1,1, 125);
    dec_iter(0,0,1,1, 126);
    dec_iter(0,0,0,1, 127);
  }
}

extern "C" void kernel_launch(void* const* d_in, const int* in_sizes, int n_in,
                              void* d_out, int out_size, void* d_ws, size_t ws_size,
                              hipStream_t stream) {
  (void)in_sizes; (void)n_in; (void)d_ws; (void)ws_size; (void)out_size;
  const float* x    = (const float*)d_in[0];
  const float* e1Wi = (const float*)d_in[1];
  const float* e1Wh = (const float*)d_in[2];
  const float* e1bi = (const float*)d_in[3];
  const float* e1bh = (const float*)d_in[4];
  const float* e2Wi = (const float*)d_in[5];
  const float* e2Wh = (const float*)d_in[6];
  const float* e2bi = (const float*)d_in[7];
  const float* e2bh = (const float*)d_in[8];
  const float* e3Wi = (const float*)d_in[9];
  const float* e3Wh = (const float*)d_in[10];
  const float* e3bi = (const float*)d_in[11];
  const float* e3bh = (const float*)d_in[12];
  const float* d1Wi = (const float*)d_in[13];
  const float* d1Wh = (const float*)d_in[14];
  const float* d1bi = (const float*)d_in[15];
  const float* d1bh = (const float*)d_in[16];
  const float* d2Wi = (const float*)d_in[17];
  const float* d2Wh = (const float*)d_in[18];
  const float* d2bi = (const float*)d_in[19];
  const float* d2bh = (const float*)d_in[20];
  const float* d3Wi = (const float*)d_in[21];
  const float* d3Wh = (const float*)d_in[22];
  const float* d3bi = (const float*)d_in[23];
  const float* d3bh = (const float*)d_in[24];
  const float* Wout = (const float*)d_in[25];
  const float* boutp= (const float*)d_in[26];
  float* out = (float*)d_out;

  lstm_ae_fused<<<512, 256, 0, stream>>>(x,
      e1Wi, e1Wh, e1bi, e1bh,
      e2Wi, e2Wh, e2bi, e2bh,
      e3Wi, e3Wh, e3bi, e3bh,
      d1Wi, d1Wh, d1bi, d1bh,
      d2Wi, d2Wh, d2bi, d2bh,
      d3Wi, d3Wh, d3bi, d3bh,
      Wout, boutp, out);
}